// Round 1
// baseline (5790.520 us; speedup 1.0000x reference)
//
#include <hip/hip_runtime.h>
#include <hip/hip_bf16.h>

#define N_NODES 170000
#define N_EDGES 1200000
#define IN_DIM 128
#define HID_DIM 128
#define OUT_DIM 64

// ---------------- degree count: one thread per edge ----------------
__global__ __launch_bounds__(256) void degree_kernel(
    const int* __restrict__ src, const int* __restrict__ dst,
    float* __restrict__ deg_out, float* __restrict__ deg_in, int nedges)
{
    int i = blockIdx.x * 256 + threadIdx.x;
    if (i < nedges) {
        unsafeAtomicAdd(&deg_out[src[i]], 1.0f);
        unsafeAtomicAdd(&deg_in[dst[i]], 1.0f);
    }
}

// ---------------- norm = 1/sqrt(max(deg,1)) in place ----------------
__global__ __launch_bounds__(256) void norm_kernel(float* __restrict__ deg, int n)
{
    int i = blockIdx.x * 256 + threadIdx.x;
    if (i < n) deg[i] = rsqrtf(fmaxf(deg[i], 1.0f));
}

// ---------------- edge aggregation: one wave per edge ----------------
// agg[dst] += h[src] * norm_out[src]
__global__ __launch_bounds__(256) void aggregate_kernel(
    const float* __restrict__ h, const int* __restrict__ src,
    const int* __restrict__ dst, const float* __restrict__ norm_out,
    float* __restrict__ agg, int nedges, int width)
{
    int wave = (int)((blockIdx.x * 256 + threadIdx.x) >> 6);
    int lane = threadIdx.x & 63;
    if (wave >= nedges) return;
    int s = src[wave];
    int d = dst[wave];
    float ns = norm_out[s];
    const float* hr = h + (size_t)s * width;
    float* ar = agg + (size_t)d * width;
    for (int c = lane; c < width; c += 64)
        unsafeAtomicAdd(&ar[c], hr[c] * ns);
}

// ---------------- fused dense: out = act((A * nin) @ W + b) ----------------
// K fixed = 128. Tile: 32 rows x 64 cols per block, 256 threads, 4x2 per thread.
__global__ __launch_bounds__(256) void matmul_kernel(
    const float* __restrict__ A, const float* __restrict__ nin,
    const float* __restrict__ W, const float* __restrict__ bias,
    float* __restrict__ out, int nrows, int outw, int relu)
{
    __shared__ float As[32][132];   // padded row stride (132 % 4 == 0 keeps float4 align)
    __shared__ float Ws[128][64];

    const int t = threadIdx.x;
    const int row0 = blockIdx.x * 32;
    const int col0 = blockIdx.y * 64;

    // Load W tile: 128 x 64 floats = 2048 float4s, 8 per thread
    #pragma unroll
    for (int i = 0; i < 8; i++) {
        int idx = t + i * 256;          // 0..2047
        int k = idx >> 4;               // /16 float4 per row
        int c4 = idx & 15;
        float4 v = *(const float4*)&W[(size_t)k * outw + col0 + c4 * 4];
        *(float4*)&Ws[k][c4 * 4] = v;
    }

    // Load A tile (scaled by nin if present): 32 x 128 floats = 1024 float4s, 4 per thread
    #pragma unroll
    for (int i = 0; i < 4; i++) {
        int idx = t + i * 256;          // 0..1023
        int r = idx >> 5;               // /32 float4 per row
        int k4 = idx & 31;
        int gr = row0 + r;
        float4 v = make_float4(0.f, 0.f, 0.f, 0.f);
        if (gr < nrows) {
            v = *(const float4*)&A[(size_t)gr * 128 + k4 * 4];
            if (nin) {
                float s = nin[gr];
                v.x *= s; v.y *= s; v.z *= s; v.w *= s;
            }
        }
        *(float4*)&As[r][k4 * 4] = v;
    }
    __syncthreads();

    const int tx = t & 31;   // col group: 2 cols
    const int ty = t >> 5;   // row group: 4 rows
    const int r0 = ty * 4;
    const int c0 = tx * 2;

    float acc[4][2] = {};
    #pragma unroll
    for (int kk = 0; kk < 128; kk += 4) {
        float4 a0 = *(const float4*)&As[r0 + 0][kk];
        float4 a1 = *(const float4*)&As[r0 + 1][kk];
        float4 a2 = *(const float4*)&As[r0 + 2][kk];
        float4 a3 = *(const float4*)&As[r0 + 3][kk];
        float2 w0 = *(const float2*)&Ws[kk + 0][c0];
        float2 w1 = *(const float2*)&Ws[kk + 1][c0];
        float2 w2 = *(const float2*)&Ws[kk + 2][c0];
        float2 w3 = *(const float2*)&Ws[kk + 3][c0];

        acc[0][0] += a0.x * w0.x; acc[0][1] += a0.x * w0.y;
        acc[1][0] += a1.x * w0.x; acc[1][1] += a1.x * w0.y;
        acc[2][0] += a2.x * w0.x; acc[2][1] += a2.x * w0.y;
        acc[3][0] += a3.x * w0.x; acc[3][1] += a3.x * w0.y;

        acc[0][0] += a0.y * w1.x; acc[0][1] += a0.y * w1.y;
        acc[1][0] += a1.y * w1.x; acc[1][1] += a1.y * w1.y;
        acc[2][0] += a2.y * w1.x; acc[2][1] += a2.y * w1.y;
        acc[3][0] += a3.y * w1.x; acc[3][1] += a3.y * w1.y;

        acc[0][0] += a0.z * w2.x; acc[0][1] += a0.z * w2.y;
        acc[1][0] += a1.z * w2.x; acc[1][1] += a1.z * w2.y;
        acc[2][0] += a2.z * w2.x; acc[2][1] += a2.z * w2.y;
        acc[3][0] += a3.z * w2.x; acc[3][1] += a3.z * w2.y;

        acc[0][0] += a0.w * w3.x; acc[0][1] += a0.w * w3.y;
        acc[1][0] += a1.w * w3.x; acc[1][1] += a1.w * w3.y;
        acc[2][0] += a2.w * w3.x; acc[2][1] += a2.w * w3.y;
        acc[3][0] += a3.w * w3.x; acc[3][1] += a3.w * w3.y;
    }

    float2 bv = make_float2(0.f, 0.f);
    if (bias) bv = *(const float2*)&bias[col0 + c0];

    #pragma unroll
    for (int i = 0; i < 4; i++) {
        int gr = row0 + r0 + i;
        if (gr < nrows) {
            float2 v;
            v.x = acc[i][0] + bv.x;
            v.y = acc[i][1] + bv.y;
            if (relu) { v.x = fmaxf(v.x, 0.f); v.y = fmaxf(v.y, 0.f); }
            *(float2*)&out[(size_t)gr * outw + col0 + c0] = v;
        }
    }
}

// ---------------- final epilogue: out = out * norm_in[row] + b2[col] ----------------
__global__ __launch_bounds__(256) void final_scale_kernel(
    float* __restrict__ out, const float* __restrict__ norm_in,
    const float* __restrict__ b2, int nrows)
{
    int idx = blockIdx.x * 256 + threadIdx.x;   // one float4 per thread
    if (idx < nrows * 16) {
        int r = idx >> 4;
        int c4 = idx & 15;
        float ni = norm_in[r];
        float4 v = *(float4*)&out[idx * 4];
        float4 b = *(const float4*)&b2[c4 * 4];
        v.x = v.x * ni + b.x;
        v.y = v.y * ni + b.y;
        v.z = v.z * ni + b.z;
        v.w = v.w * ni + b.w;
        *(float4*)&out[idx * 4] = v;
    }
}

extern "C" void kernel_launch(void* const* d_in, const int* in_sizes, int n_in,
                              void* d_out, int out_size, void* d_ws, size_t ws_size,
                              hipStream_t stream)
{
    const float* feat = (const float*)d_in[0];
    const int* src    = (const int*)d_in[1];
    const int* dst    = (const int*)d_in[2];
    const float* W0   = (const float*)d_in[3];
    const float* b0   = (const float*)d_in[4];
    const float* W1   = (const float*)d_in[5];
    const float* b1   = (const float*)d_in[6];
    const float* W2   = (const float*)d_in[7];
    const float* b2   = (const float*)d_in[8];
    float* out = (float*)d_out;

    const int N = N_NODES;
    const int E = N_EDGES;

    float* ws = (float*)d_ws;
    float* norm_out = ws;                       // N
    float* norm_in  = ws + N;                   // N
    float* bufA     = ws + 2 * (size_t)N;       // N*128
    float* bufB     = bufA + (size_t)N * 128;   // N*128

    // Degrees + norms
    hipMemsetAsync(norm_out, 0, 2 * (size_t)N * sizeof(float), stream);
    degree_kernel<<<(E + 255) / 256, 256, 0, stream>>>(src, dst, norm_out, norm_in, E);
    norm_kernel<<<(2 * N + 255) / 256, 256, 0, stream>>>(norm_out, 2 * N);

    const int aggBlocks = (E + 3) / 4;          // 4 waves/block, 1 edge/wave
    const int rowBlocks = (N + 31) / 32;

    // ---- Layer 1: agg(feat) -> (agg*nin)@W0+b0, relu -> bufB
    hipMemsetAsync(bufA, 0, (size_t)N * 128 * sizeof(float), stream);
    aggregate_kernel<<<aggBlocks, 256, 0, stream>>>(feat, src, dst, norm_out, bufA, E, 128);
    matmul_kernel<<<dim3(rowBlocks, 2), 256, 0, stream>>>(bufA, norm_in, W0, b0, bufB, N, 128, 1);

    // ---- Layer 2: agg(bufB) -> (agg*nin)@W1+b1, relu -> bufB
    hipMemsetAsync(bufA, 0, (size_t)N * 128 * sizeof(float), stream);
    aggregate_kernel<<<aggBlocks, 256, 0, stream>>>(bufB, src, dst, norm_out, bufA, E, 128);
    matmul_kernel<<<dim3(rowBlocks, 2), 256, 0, stream>>>(bufA, norm_in, W1, b1, bufB, N, 128, 1);

    // ---- Layer 3 (commuted): t = h2@W2 (no scale/bias/relu) -> bufA (N x 64)
    matmul_kernel<<<dim3(rowBlocks, 1), 256, 0, stream>>>(bufB, nullptr, W2, nullptr, bufA, N, 64, 0);
    // aggregate 64-wide t into d_out, then out = out*norm_in + b2
    hipMemsetAsync(out, 0, (size_t)N * 64 * sizeof(float), stream);
    aggregate_kernel<<<aggBlocks, 256, 0, stream>>>(bufA, src, dst, norm_out, out, E, 64);
    final_scale_kernel<<<(N * 16 + 255) / 256, 256, 0, stream>>>(out, norm_in, b2, N);
}

// Round 2
// 1776.169 us; speedup vs baseline: 3.2601x; 3.2601x over previous
//
#include <hip/hip_runtime.h>
#include <hip/hip_bf16.h>

#define N_NODES 170000
#define N_EDGES 1200000
#define IN_DIM 128
#define HID_DIM 128
#define OUT_DIM 64

// ---------------- degree count: one thread per edge ----------------
__global__ __launch_bounds__(256) void degree_kernel(
    const int* __restrict__ src, const int* __restrict__ dst,
    float* __restrict__ deg_out, float* __restrict__ deg_in, int nedges)
{
    int i = blockIdx.x * 256 + threadIdx.x;
    if (i < nedges) {
        unsafeAtomicAdd(&deg_out[src[i]], 1.0f);
        unsafeAtomicAdd(&deg_in[dst[i]], 1.0f);
    }
}

// ---------------- norm = 1/sqrt(max(deg,1)) in place ----------------
__global__ __launch_bounds__(256) void norm_kernel(float* __restrict__ deg, int n)
{
    int i = blockIdx.x * 256 + threadIdx.x;
    if (i < n) deg[i] = rsqrtf(fmaxf(deg[i], 1.0f));
}

// ---------------- edge aggregation: one wave per edge ----------------
// agg[dst] += h[src] * norm_out[src]
__global__ __launch_bounds__(256) void aggregate_kernel(
    const float* __restrict__ h, const int* __restrict__ src,
    const int* __restrict__ dst, const float* __restrict__ norm_out,
    float* __restrict__ agg, int nedges, int width)
{
    int wave = (int)((blockIdx.x * 256 + threadIdx.x) >> 6);
    int lane = threadIdx.x & 63;
    if (wave >= nedges) return;
    int s = src[wave];
    int d = dst[wave];
    float ns = norm_out[s];
    const float* hr = h + (size_t)s * width;
    float* ar = agg + (size_t)d * width;
    for (int c = lane; c < width; c += 64)
        unsafeAtomicAdd(&ar[c], hr[c] * ns);
}

// ---------------- fused dense: out = act((A * nin) @ W + b) ----------------
// K fixed = 128. Tile: 64 rows x 64 cols per block, 256 threads, 4x4 per thread.
// #pragma unroll 2 on the k-loop: bounded unroll so the compiler cannot hoist
// all 32 bodies' LDS loads (R1's full unroll spilled: VGPR=256, 2.9 GB scratch
// writes, 1.6 ms/dispatch).
__global__ __launch_bounds__(256) void matmul_kernel(
    const float* __restrict__ A, const float* __restrict__ nin,
    const float* __restrict__ W, const float* __restrict__ bias,
    float* __restrict__ out, int nrows, int outw, int relu)
{
    __shared__ float As[64][132];   // pad: ty-stride 528 % 32 banks = 16 -> 2-way (free)
    __shared__ float Ws[128][64];

    const int t = threadIdx.x;
    const int row0 = blockIdx.x * 64;
    const int col0 = blockIdx.y * 64;

    // Load W tile: 128 x 64 floats = 2048 float4s, 8 per thread
    #pragma unroll
    for (int i = 0; i < 8; i++) {
        int idx = t + i * 256;          // 0..2047
        int k = idx >> 4;               // 16 float4 per row
        int c4 = idx & 15;
        float4 v = *(const float4*)&W[(size_t)k * outw + col0 + c4 * 4];
        *(float4*)&Ws[k][c4 * 4] = v;
    }

    // Load A tile (scaled by nin if present): 64 x 128 floats = 2048 float4s, 8/thread
    #pragma unroll
    for (int i = 0; i < 8; i++) {
        int idx = t + i * 256;          // 0..2047
        int r = idx >> 5;               // 32 float4 per row
        int k4 = idx & 31;
        int gr = row0 + r;
        float4 v = make_float4(0.f, 0.f, 0.f, 0.f);
        if (gr < nrows) {
            v = *(const float4*)&A[(size_t)gr * 128 + k4 * 4];
            if (nin) {
                float s = nin[gr];
                v.x *= s; v.y *= s; v.z *= s; v.w *= s;
            }
        }
        *(float4*)&As[r][k4 * 4] = v;
    }
    __syncthreads();

    const int tx = t & 15;   // col group: 4 cols
    const int ty = t >> 4;   // row group: 4 rows
    const int r0 = ty * 4;
    const int c0 = tx * 4;

    float acc[4][4] = {};
    #pragma unroll 2
    for (int kk = 0; kk < 128; kk += 4) {
        float4 a0 = *(const float4*)&As[r0 + 0][kk];
        float4 a1 = *(const float4*)&As[r0 + 1][kk];
        float4 a2 = *(const float4*)&As[r0 + 2][kk];
        float4 a3 = *(const float4*)&As[r0 + 3][kk];
        float4 w0 = *(const float4*)&Ws[kk + 0][c0];
        float4 w1 = *(const float4*)&Ws[kk + 1][c0];
        float4 w2 = *(const float4*)&Ws[kk + 2][c0];
        float4 w3 = *(const float4*)&Ws[kk + 3][c0];

        #define STEP(av, wv) \
            acc[0][0] += a0.av * wv.x; acc[0][1] += a0.av * wv.y; \
            acc[0][2] += a0.av * wv.z; acc[0][3] += a0.av * wv.w; \
            acc[1][0] += a1.av * wv.x; acc[1][1] += a1.av * wv.y; \
            acc[1][2] += a1.av * wv.z; acc[1][3] += a1.av * wv.w; \
            acc[2][0] += a2.av * wv.x; acc[2][1] += a2.av * wv.y; \
            acc[2][2] += a2.av * wv.z; acc[2][3] += a2.av * wv.w; \
            acc[3][0] += a3.av * wv.x; acc[3][1] += a3.av * wv.y; \
            acc[3][2] += a3.av * wv.z; acc[3][3] += a3.av * wv.w;
        STEP(x, w0)
        STEP(y, w1)
        STEP(z, w2)
        STEP(w, w3)
        #undef STEP
    }

    float4 bv = make_float4(0.f, 0.f, 0.f, 0.f);
    if (bias) bv = *(const float4*)&bias[col0 + c0];

    #pragma unroll
    for (int i = 0; i < 4; i++) {
        int gr = row0 + r0 + i;
        if (gr < nrows) {
            float4 v;
            v.x = acc[i][0] + bv.x;
            v.y = acc[i][1] + bv.y;
            v.z = acc[i][2] + bv.z;
            v.w = acc[i][3] + bv.w;
            if (relu) {
                v.x = fmaxf(v.x, 0.f); v.y = fmaxf(v.y, 0.f);
                v.z = fmaxf(v.z, 0.f); v.w = fmaxf(v.w, 0.f);
            }
            *(float4*)&out[(size_t)gr * outw + col0 + c0] = v;
        }
    }
}

// ---------------- final epilogue: out = out * norm_in[row] + b2[col] ----------------
__global__ __launch_bounds__(256) void final_scale_kernel(
    float* __restrict__ out, const float* __restrict__ norm_in,
    const float* __restrict__ b2, int nrows)
{
    int idx = blockIdx.x * 256 + threadIdx.x;   // one float4 per thread
    if (idx < nrows * 16) {
        int r = idx >> 4;
        int c4 = idx & 15;
        float ni = norm_in[r];
        float4 v = *(float4*)&out[idx * 4];
        float4 b = *(const float4*)&b2[c4 * 4];
        v.x = v.x * ni + b.x;
        v.y = v.y * ni + b.y;
        v.z = v.z * ni + b.z;
        v.w = v.w * ni + b.w;
        *(float4*)&out[idx * 4] = v;
    }
}

extern "C" void kernel_launch(void* const* d_in, const int* in_sizes, int n_in,
                              void* d_out, int out_size, void* d_ws, size_t ws_size,
                              hipStream_t stream)
{
    const float* feat = (const float*)d_in[0];
    const int* src    = (const int*)d_in[1];
    const int* dst    = (const int*)d_in[2];
    const float* W0   = (const float*)d_in[3];
    const float* b0   = (const float*)d_in[4];
    const float* W1   = (const float*)d_in[5];
    const float* b1   = (const float*)d_in[6];
    const float* W2   = (const float*)d_in[7];
    const float* b2   = (const float*)d_in[8];
    float* out = (float*)d_out;

    const int N = N_NODES;
    const int E = N_EDGES;

    float* ws = (float*)d_ws;
    float* norm_out = ws;                       // N
    float* norm_in  = ws + N;                   // N
    float* bufA     = ws + 2 * (size_t)N;       // N*128
    float* bufB     = bufA + (size_t)N * 128;   // N*128

    // Degrees + norms
    hipMemsetAsync(norm_out, 0, 2 * (size_t)N * sizeof(float), stream);
    degree_kernel<<<(E + 255) / 256, 256, 0, stream>>>(src, dst, norm_out, norm_in, E);
    norm_kernel<<<(2 * N + 255) / 256, 256, 0, stream>>>(norm_out, 2 * N);

    const int aggBlocks = (E + 3) / 4;          // 4 waves/block, 1 edge/wave
    const int rowBlocks = (N + 63) / 64;

    // ---- Layer 1: agg(feat) -> (agg*nin)@W0+b0, relu -> bufB
    hipMemsetAsync(bufA, 0, (size_t)N * 128 * sizeof(float), stream);
    aggregate_kernel<<<aggBlocks, 256, 0, stream>>>(feat, src, dst, norm_out, bufA, E, 128);
    matmul_kernel<<<dim3(rowBlocks, 2), 256, 0, stream>>>(bufA, norm_in, W0, b0, bufB, N, 128, 1);

    // ---- Layer 2: agg(bufB) -> (agg*nin)@W1+b1, relu -> bufB
    hipMemsetAsync(bufA, 0, (size_t)N * 128 * sizeof(float), stream);
    aggregate_kernel<<<aggBlocks, 256, 0, stream>>>(bufB, src, dst, norm_out, bufA, E, 128);
    matmul_kernel<<<dim3(rowBlocks, 2), 256, 0, stream>>>(bufA, norm_in, W1, b1, bufB, N, 128, 1);

    // ---- Layer 3 (commuted): t = h2@W2 (no scale/bias/relu) -> bufA (N x 64)
    matmul_kernel<<<dim3(rowBlocks, 1), 256, 0, stream>>>(bufB, nullptr, W2, nullptr, bufA, N, 64, 0);
    // aggregate 64-wide t into d_out, then out = out*norm_in + b2
    hipMemsetAsync(out, 0, (size_t)N * 64 * sizeof(float), stream);
    aggregate_kernel<<<aggBlocks, 256, 0, stream>>>(bufA, src, dst, norm_out, out, E, 64);
    final_scale_kernel<<<(N * 16 + 255) / 256, 256, 0, stream>>>(out, norm_in, b2, N);
}

// Round 3
// 915.164 us; speedup vs baseline: 6.3273x; 1.9408x over previous
//
#include <hip/hip_runtime.h>
#include <hip/hip_bf16.h>

#define N_NODES 170000
#define N_EDGES 1200000
#define SCAN_PAD 171008          // 167 blocks * 1024
#define NB_SCAN 167

// ---------------- histogram: in/out degree counts (int atomics) ----------------
__global__ __launch_bounds__(256) void hist_kernel(
    const int* __restrict__ src, const int* __restrict__ dst,
    int* __restrict__ cnt_out, int* __restrict__ cnt_in, int nedges)
{
    int i = blockIdx.x * 256 + threadIdx.x;
    if (i < nedges) {
        atomicAdd(&cnt_out[src[i]], 1);
        atomicAdd(&cnt_in[dst[i]], 1);
    }
}

// ---------------- norm = 1/sqrt(max(cnt,1)) ----------------
__global__ __launch_bounds__(256) void norm_kernel(
    const int* __restrict__ cnt, float* __restrict__ norm, int n)
{
    int i = blockIdx.x * 256 + threadIdx.x;
    if (i < n) norm[i] = rsqrtf(fmaxf((float)cnt[i], 1.0f));
}

// ---------------- 3-phase exclusive scan of cnt_in -> row_start ----------------
// Phase 1: each block scans 1024 elements (256 thr x 4), writes partials + block sum
__global__ __launch_bounds__(256) void scan1_kernel(
    const int* __restrict__ in, int* __restrict__ partial,
    int* __restrict__ blockSums, int n)
{
    __shared__ int sdata[256];
    int t = threadIdx.x;
    int base = blockIdx.x * 1024 + t * 4;
    int4 v = make_int4(0, 0, 0, 0);
    if (base + 3 < n) v = *(const int4*)&in[base];
    else {
        if (base + 0 < n) v.x = in[base + 0];
        if (base + 1 < n) v.y = in[base + 1];
        if (base + 2 < n) v.z = in[base + 2];
        if (base + 3 < n) v.w = in[base + 3];
    }
    int tsum = v.x + v.y + v.z + v.w;
    sdata[t] = tsum;
    __syncthreads();
    for (int off = 1; off < 256; off <<= 1) {
        int add = 0;
        if (t >= off) add = sdata[t - off];
        __syncthreads();
        if (t >= off) sdata[t] += add;
        __syncthreads();
    }
    int excl = sdata[t] - tsum;
    int4 o;
    o.x = excl;
    o.y = o.x + v.x;
    o.z = o.y + v.y;
    o.w = o.z + v.z;
    *(int4*)&partial[base] = o;   // partial buffer padded to SCAN_PAD+4
    if (t == 255) blockSums[blockIdx.x] = sdata[255];
}

// Phase 2: single block exclusive-scans blockSums (NB <= 256)
__global__ __launch_bounds__(256) void scan2_kernel(int* __restrict__ blockSums, int nb)
{
    __shared__ int sdata[256];
    int t = threadIdx.x;
    int val = (t < nb) ? blockSums[t] : 0;
    sdata[t] = val;
    __syncthreads();
    for (int off = 1; off < 256; off <<= 1) {
        int add = 0;
        if (t >= off) add = sdata[t - off];
        __syncthreads();
        if (t >= off) sdata[t] += add;
        __syncthreads();
    }
    if (t < nb) blockSums[t] = sdata[t] - val;   // exclusive
}

// Phase 3: add block offsets; emit row_start (in place) and cursor copy
__global__ __launch_bounds__(256) void scan3_kernel(
    int* __restrict__ row_start, int* __restrict__ cursor,
    const int* __restrict__ blockSums)
{
    int off = blockSums[blockIdx.x];
    int base = blockIdx.x * 1024 + threadIdx.x * 4;
    int4 v = *(const int4*)&row_start[base];
    v.x += off; v.y += off; v.z += off; v.w += off;
    *(int4*)&row_start[base] = v;
    *(int4*)&cursor[base] = v;
}

// ---------------- scatter src ids into dst-sorted CSR ----------------
__global__ __launch_bounds__(256) void scatter_kernel(
    const int* __restrict__ src, const int* __restrict__ dst,
    int* __restrict__ cursor, int* __restrict__ csr, int nedges)
{
    int i = blockIdx.x * 256 + threadIdx.x;
    if (i < nedges) {
        int p = atomicAdd(&cursor[dst[i]], 1);
        csr[p] = src[i];
    }
}

// ---------------- pull aggregation: one wave per dst row ----------------
// out[d] = norm_in[d] * sum_{s in in(d)} h[s] * (SCALE_SRC ? norm_out[s] : 1)  (+ bias)
template<int W, bool SCALE_SRC, bool BIAS>
__global__ __launch_bounds__(256) void gather_kernel(
    const float* __restrict__ h, const int* __restrict__ csr,
    const int* __restrict__ row_start, const float* __restrict__ norm_out,
    const float* __restrict__ norm_in, const float* __restrict__ bias,
    float* __restrict__ out)
{
    int wave = (int)((blockIdx.x * 256 + threadIdx.x) >> 6);
    int lane = threadIdx.x & 63;
    if (wave >= N_NODES) return;
    int beg = row_start[wave];
    int end = row_start[wave + 1];
    float acc0 = 0.f, acc1 = 0.f;
    for (int j = beg; j < end; j += 64) {
        int cnt = min(64, end - j);
        int sv = 0;
        float nv = 0.f;
        if (j + lane < end) {
            sv = csr[j + lane];                       // coalesced edge-id load
            if (SCALE_SRC) nv = norm_out[sv];
        }
        for (int i = 0; i < cnt; i++) {
            int s = __shfl(sv, i);
            if (W == 128) {
                float2 v = *(const float2*)&h[(size_t)s * 128 + lane * 2];
                if (SCALE_SRC) {
                    float sc = __shfl(nv, i);
                    v.x *= sc; v.y *= sc;
                }
                acc0 += v.x; acc1 += v.y;
            } else {
                acc0 += h[(size_t)s * 64 + lane];
            }
        }
    }
    float ni = norm_in[wave];
    if (W == 128) {
        float2 o;
        o.x = acc0 * ni;
        o.y = acc1 * ni;
        *(float2*)&out[(size_t)wave * 128 + lane * 2] = o;
    } else {
        float o = acc0 * ni;
        if (BIAS) o += bias[lane];
        out[(size_t)wave * 64 + lane] = o;
    }
}

// ---------------- fused dense: out = act(A @ W + b) * rowscale ----------------
// K fixed = 128. Tile: 64 rows x 64 cols per block, 256 threads, 4x4 per thread.
// #pragma unroll 2: bounded so the compiler can't hoist all 32 bodies (R1 full
// unroll spilled: VGPR=256, 2.9 GB scratch writes).
__global__ __launch_bounds__(256) void matmul_kernel(
    const float* __restrict__ A, const float* __restrict__ W,
    const float* __restrict__ bias, const float* __restrict__ rowscale,
    float* __restrict__ out, int nrows, int outw, int relu)
{
    __shared__ float As[64][132];
    __shared__ float Ws[128][64];

    const int t = threadIdx.x;
    const int row0 = blockIdx.x * 64;
    const int col0 = blockIdx.y * 64;

    #pragma unroll
    for (int i = 0; i < 8; i++) {
        int idx = t + i * 256;
        int k = idx >> 4;
        int c4 = idx & 15;
        float4 v = *(const float4*)&W[(size_t)k * outw + col0 + c4 * 4];
        *(float4*)&Ws[k][c4 * 4] = v;
    }

    #pragma unroll
    for (int i = 0; i < 8; i++) {
        int idx = t + i * 256;
        int r = idx >> 5;
        int k4 = idx & 31;
        int gr = row0 + r;
        float4 v = make_float4(0.f, 0.f, 0.f, 0.f);
        if (gr < nrows) v = *(const float4*)&A[(size_t)gr * 128 + k4 * 4];
        *(float4*)&As[r][k4 * 4] = v;
    }
    __syncthreads();

    const int tx = t & 15;
    const int ty = t >> 4;
    const int r0 = ty * 4;
    const int c0 = tx * 4;

    float acc[4][4] = {};
    #pragma unroll 2
    for (int kk = 0; kk < 128; kk += 4) {
        float4 a0 = *(const float4*)&As[r0 + 0][kk];
        float4 a1 = *(const float4*)&As[r0 + 1][kk];
        float4 a2 = *(const float4*)&As[r0 + 2][kk];
        float4 a3 = *(const float4*)&As[r0 + 3][kk];
        float4 w0 = *(const float4*)&Ws[kk + 0][c0];
        float4 w1 = *(const float4*)&Ws[kk + 1][c0];
        float4 w2 = *(const float4*)&Ws[kk + 2][c0];
        float4 w3 = *(const float4*)&Ws[kk + 3][c0];

        #define STEP(av, wv) \
            acc[0][0] += a0.av * wv.x; acc[0][1] += a0.av * wv.y; \
            acc[0][2] += a0.av * wv.z; acc[0][3] += a0.av * wv.w; \
            acc[1][0] += a1.av * wv.x; acc[1][1] += a1.av * wv.y; \
            acc[1][2] += a1.av * wv.z; acc[1][3] += a1.av * wv.w; \
            acc[2][0] += a2.av * wv.x; acc[2][1] += a2.av * wv.y; \
            acc[2][2] += a2.av * wv.z; acc[2][3] += a2.av * wv.w; \
            acc[3][0] += a3.av * wv.x; acc[3][1] += a3.av * wv.y; \
            acc[3][2] += a3.av * wv.z; acc[3][3] += a3.av * wv.w;
        STEP(x, w0)
        STEP(y, w1)
        STEP(z, w2)
        STEP(w, w3)
        #undef STEP
    }

    float4 bv = make_float4(0.f, 0.f, 0.f, 0.f);
    if (bias) bv = *(const float4*)&bias[col0 + c0];

    #pragma unroll
    for (int i = 0; i < 4; i++) {
        int gr = row0 + r0 + i;
        if (gr < nrows) {
            float4 v;
            v.x = acc[i][0] + bv.x;
            v.y = acc[i][1] + bv.y;
            v.z = acc[i][2] + bv.z;
            v.w = acc[i][3] + bv.w;
            if (relu) {
                v.x = fmaxf(v.x, 0.f); v.y = fmaxf(v.y, 0.f);
                v.z = fmaxf(v.z, 0.f); v.w = fmaxf(v.w, 0.f);
            }
            if (rowscale) {
                float rs = rowscale[gr];
                v.x *= rs; v.y *= rs; v.z *= rs; v.w *= rs;
            }
            *(float4*)&out[(size_t)gr * outw + col0 + c0] = v;
        }
    }
}

extern "C" void kernel_launch(void* const* d_in, const int* in_sizes, int n_in,
                              void* d_out, int out_size, void* d_ws, size_t ws_size,
                              hipStream_t stream)
{
    const float* feat = (const float*)d_in[0];
    const int* src    = (const int*)d_in[1];
    const int* dst    = (const int*)d_in[2];
    const float* W0   = (const float*)d_in[3];
    const float* b0   = (const float*)d_in[4];
    const float* W1   = (const float*)d_in[5];
    const float* b1   = (const float*)d_in[6];
    const float* W2   = (const float*)d_in[7];
    const float* b2   = (const float*)d_in[8];
    float* out = (float*)d_out;

    const int N = N_NODES;
    const int E = N_EDGES;

    // ---- workspace layout (4-byte units) ----
    char* ws = (char*)d_ws;
    float* norm_out = (float*)ws;                    // N
    float* norm_in  = norm_out + N;                  // N
    int* cnt_out    = (int*)(norm_in + N);           // N
    int* cnt_in     = cnt_out + N;                   // N   (contiguous w/ cnt_out)
    int* row_start  = cnt_in + N;                    // SCAN_PAD + 4
    int* cursor     = row_start + (SCAN_PAD + 4);    // SCAN_PAD
    int* blockSums  = cursor + SCAN_PAD;             // 256
    int* csr        = blockSums + 268;               // E (268 keeps 16B alignment)
    float* bufA     = (float*)(csr + E);             // N*128
    float* bufB     = bufA + (size_t)N * 128;        // N*128

    // ---- CSR build ----
    hipMemsetAsync(cnt_out, 0, 2 * (size_t)N * sizeof(int), stream);
    hist_kernel<<<(E + 255) / 256, 256, 0, stream>>>(src, dst, cnt_out, cnt_in, E);
    norm_kernel<<<(2 * N + 255) / 256, 256, 0, stream>>>(cnt_out, norm_out, 2 * N);
    scan1_kernel<<<NB_SCAN, 256, 0, stream>>>(cnt_in, row_start, blockSums, N);
    scan2_kernel<<<1, 256, 0, stream>>>(blockSums, NB_SCAN);
    scan3_kernel<<<NB_SCAN, 256, 0, stream>>>(row_start, cursor, blockSums);
    scatter_kernel<<<(E + 255) / 256, 256, 0, stream>>>(src, dst, cursor, csr, E);

    const int gatherBlocks = (N + 3) / 4;            // 1 wave/row, 4 waves/block
    const int rowBlocks = (N + 63) / 64;

    // ---- Layer 1: pull-agg(feat*norm_out)*norm_in -> bufA; relu(bufA@W0+b0)*norm_out -> bufB
    gather_kernel<128, true, false><<<gatherBlocks, 256, 0, stream>>>(
        feat, csr, row_start, norm_out, norm_in, nullptr, bufA);
    matmul_kernel<<<dim3(rowBlocks, 2), 256, 0, stream>>>(bufA, W0, b0, norm_out, bufB, N, 128, 1);

    // ---- Layer 2: pull-agg(bufB)*norm_in -> bufA; relu(bufA@W1+b1)*norm_out -> bufB
    gather_kernel<128, false, false><<<gatherBlocks, 256, 0, stream>>>(
        bufB, csr, row_start, nullptr, norm_in, nullptr, bufA);
    matmul_kernel<<<dim3(rowBlocks, 2), 256, 0, stream>>>(bufA, W1, b1, norm_out, bufB, N, 128, 1);

    // ---- Layer 3 (commuted): t = bufB@W2 -> bufA (N x 64); out = pull-agg(t)*norm_in + b2
    matmul_kernel<<<dim3(rowBlocks, 1), 256, 0, stream>>>(bufB, W2, nullptr, nullptr, bufA, N, 64, 0);
    gather_kernel<64, false, true><<<gatherBlocks, 256, 0, stream>>>(
        bufA, csr, row_start, nullptr, norm_in, b2, out);
}

// Round 4
// 844.193 us; speedup vs baseline: 6.8592x; 1.0841x over previous
//
#include <hip/hip_runtime.h>
#include <hip/hip_bf16.h>

#define N_NODES 170000
#define N_EDGES 1200000
#define SCAN_PAD 171008          // 167 blocks * 1024
#define NB_SCAN 167

// ---------------- histogram: in/out degree counts (int atomics) ----------------
__global__ __launch_bounds__(256) void hist_kernel(
    const int* __restrict__ src, const int* __restrict__ dst,
    int* __restrict__ cnt_out, int* __restrict__ cnt_in, int nedges)
{
    int i = blockIdx.x * 256 + threadIdx.x;
    if (i < nedges) {
        atomicAdd(&cnt_out[src[i]], 1);
        atomicAdd(&cnt_in[dst[i]], 1);
    }
}

// ---------------- norm = 1/sqrt(max(cnt,1)) ----------------
__global__ __launch_bounds__(256) void norm_kernel(
    const int* __restrict__ cnt, float* __restrict__ norm, int n)
{
    int i = blockIdx.x * 256 + threadIdx.x;
    if (i < n) norm[i] = rsqrtf(fmaxf((float)cnt[i], 1.0f));
}

// ---------------- 3-phase exclusive scan of cnt_in -> row_start ----------------
__global__ __launch_bounds__(256) void scan1_kernel(
    const int* __restrict__ in, int* __restrict__ partial,
    int* __restrict__ blockSums, int n)
{
    __shared__ int sdata[256];
    int t = threadIdx.x;
    int base = blockIdx.x * 1024 + t * 4;
    int4 v = make_int4(0, 0, 0, 0);
    if (base + 3 < n) v = *(const int4*)&in[base];
    else {
        if (base + 0 < n) v.x = in[base + 0];
        if (base + 1 < n) v.y = in[base + 1];
        if (base + 2 < n) v.z = in[base + 2];
        if (base + 3 < n) v.w = in[base + 3];
    }
    int tsum = v.x + v.y + v.z + v.w;
    sdata[t] = tsum;
    __syncthreads();
    for (int off = 1; off < 256; off <<= 1) {
        int add = 0;
        if (t >= off) add = sdata[t - off];
        __syncthreads();
        if (t >= off) sdata[t] += add;
        __syncthreads();
    }
    int excl = sdata[t] - tsum;
    int4 o;
    o.x = excl;
    o.y = o.x + v.x;
    o.z = o.y + v.y;
    o.w = o.z + v.z;
    *(int4*)&partial[base] = o;   // partial buffer padded to SCAN_PAD+4
    if (t == 255) blockSums[blockIdx.x] = sdata[255];
}

__global__ __launch_bounds__(256) void scan2_kernel(int* __restrict__ blockSums, int nb)
{
    __shared__ int sdata[256];
    int t = threadIdx.x;
    int val = (t < nb) ? blockSums[t] : 0;
    sdata[t] = val;
    __syncthreads();
    for (int off = 1; off < 256; off <<= 1) {
        int add = 0;
        if (t >= off) add = sdata[t - off];
        __syncthreads();
        if (t >= off) sdata[t] += add;
        __syncthreads();
    }
    if (t < nb) blockSums[t] = sdata[t] - val;   // exclusive
}

__global__ __launch_bounds__(256) void scan3_kernel(
    int* __restrict__ row_start, int* __restrict__ cursor,
    const int* __restrict__ blockSums)
{
    int off = blockSums[blockIdx.x];
    int base = blockIdx.x * 1024 + threadIdx.x * 4;
    int4 v = *(const int4*)&row_start[base];
    v.x += off; v.y += off; v.z += off; v.w += off;
    *(int4*)&row_start[base] = v;
    *(int4*)&cursor[base] = v;
}

// ---------------- scatter src ids into dst-sorted CSR ----------------
__global__ __launch_bounds__(256) void scatter_kernel(
    const int* __restrict__ src, const int* __restrict__ dst,
    int* __restrict__ cursor, int* __restrict__ csr, int nedges)
{
    int i = blockIdx.x * 256 + threadIdx.x;
    if (i < nedges) {
        int p = atomicAdd(&cursor[dst[i]], 1);
        csr[p] = src[i];
    }
}

// ---------------- pull aggregation: 16-lane group per dst row ----------------
// R3 post-mortem: one wave/row had a single dependent-load chain (avg degree ~7)
// -> latency-bound at 35% HBM. 16-lane groups give 4 independent rows per wave
// and 2 independent float4 loads per edge -> ~8x memory-level parallelism.
// out[d] = norm_in[d] * sum_{s in in(d)} h[s] * (SCALE_SRC ? norm_out[s] : 1)  (+ bias)
template<int W, bool SCALE_SRC, bool BIAS>
__global__ __launch_bounds__(256) void gather_kernel(
    const float* __restrict__ h, const int* __restrict__ csr,
    const int* __restrict__ row_start, const float* __restrict__ norm_out,
    const float* __restrict__ norm_in, const float* __restrict__ bias,
    float* __restrict__ out)
{
    int tid = blockIdx.x * 256 + threadIdx.x;
    int row = tid >> 4;                 // 16 lanes per row
    int l = threadIdx.x & 15;           // lane within group
    int gbase = threadIdx.x & 48;       // group's base lane within the wave
    if (row >= N_NODES) return;
    int beg = row_start[row];
    int end = row_start[row + 1];
    float4 acc0 = make_float4(0.f, 0.f, 0.f, 0.f);
    float4 acc1 = make_float4(0.f, 0.f, 0.f, 0.f);
    for (int j = beg; j < end; j += 16) {
        int cnt = min(16, end - j);
        int sv = 0;
        float nv = 0.f;
        if (j + l < end) {
            sv = csr[j + l];                       // coalesced edge-id load
            if (SCALE_SRC) nv = norm_out[sv];
        }
        for (int i = 0; i < cnt; i++) {
            int s = __shfl(sv, gbase + i);
            const float4* hp = (const float4*)&h[(size_t)s * W];
            if (W == 128) {
                float4 v0 = hp[l];
                float4 v1 = hp[l + 16];
                if (SCALE_SRC) {
                    float sc = __shfl(nv, gbase + i);
                    acc0.x += v0.x * sc; acc0.y += v0.y * sc;
                    acc0.z += v0.z * sc; acc0.w += v0.w * sc;
                    acc1.x += v1.x * sc; acc1.y += v1.y * sc;
                    acc1.z += v1.z * sc; acc1.w += v1.w * sc;
                } else {
                    acc0.x += v0.x; acc0.y += v0.y; acc0.z += v0.z; acc0.w += v0.w;
                    acc1.x += v1.x; acc1.y += v1.y; acc1.z += v1.z; acc1.w += v1.w;
                }
            } else {                    // W == 64: one float4 per lane covers the row
                float4 v0 = hp[l];
                acc0.x += v0.x; acc0.y += v0.y; acc0.z += v0.z; acc0.w += v0.w;
            }
        }
    }
    float ni = norm_in[row];
    if (W == 128) {
        acc0.x *= ni; acc0.y *= ni; acc0.z *= ni; acc0.w *= ni;
        acc1.x *= ni; acc1.y *= ni; acc1.z *= ni; acc1.w *= ni;
        float4* op = (float4*)&out[(size_t)row * 128];
        op[l] = acc0;
        op[l + 16] = acc1;
    } else {
        acc0.x *= ni; acc0.y *= ni; acc0.z *= ni; acc0.w *= ni;
        if (BIAS) {
            float4 b = *(const float4*)&bias[l * 4];
            acc0.x += b.x; acc0.y += b.y; acc0.z += b.z; acc0.w += b.w;
        }
        *(float4*)&out[(size_t)row * 64 + l * 4] = acc0;
    }
}

// ---------------- fused dense: out = act(A @ W + b) * rowscale ----------------
// K fixed = 128. Tile: 64 rows x 64 cols per block, 256 threads, 4x4 per thread.
// #pragma unroll 2: bounded so the compiler can't hoist all 32 bodies (R1 full
// unroll spilled: VGPR=256, 2.9 GB scratch writes).
__global__ __launch_bounds__(256) void matmul_kernel(
    const float* __restrict__ A, const float* __restrict__ W,
    const float* __restrict__ bias, const float* __restrict__ rowscale,
    float* __restrict__ out, int nrows, int outw, int relu)
{
    __shared__ float As[64][132];
    __shared__ float Ws[128][64];

    const int t = threadIdx.x;
    const int row0 = blockIdx.x * 64;
    const int col0 = blockIdx.y * 64;

    #pragma unroll
    for (int i = 0; i < 8; i++) {
        int idx = t + i * 256;
        int k = idx >> 4;
        int c4 = idx & 15;
        float4 v = *(const float4*)&W[(size_t)k * outw + col0 + c4 * 4];
        *(float4*)&Ws[k][c4 * 4] = v;
    }

    #pragma unroll
    for (int i = 0; i < 8; i++) {
        int idx = t + i * 256;
        int r = idx >> 5;
        int k4 = idx & 31;
        int gr = row0 + r;
        float4 v = make_float4(0.f, 0.f, 0.f, 0.f);
        if (gr < nrows) v = *(const float4*)&A[(size_t)gr * 128 + k4 * 4];
        *(float4*)&As[r][k4 * 4] = v;
    }
    __syncthreads();

    const int tx = t & 15;
    const int ty = t >> 4;
    const int r0 = ty * 4;
    const int c0 = tx * 4;

    float acc[4][4] = {};
    #pragma unroll 2
    for (int kk = 0; kk < 128; kk += 4) {
        float4 a0 = *(const float4*)&As[r0 + 0][kk];
        float4 a1 = *(const float4*)&As[r0 + 1][kk];
        float4 a2 = *(const float4*)&As[r0 + 2][kk];
        float4 a3 = *(const float4*)&As[r0 + 3][kk];
        float4 w0 = *(const float4*)&Ws[kk + 0][c0];
        float4 w1 = *(const float4*)&Ws[kk + 1][c0];
        float4 w2 = *(const float4*)&Ws[kk + 2][c0];
        float4 w3 = *(const float4*)&Ws[kk + 3][c0];

        #define STEP(av, wv) \
            acc[0][0] += a0.av * wv.x; acc[0][1] += a0.av * wv.y; \
            acc[0][2] += a0.av * wv.z; acc[0][3] += a0.av * wv.w; \
            acc[1][0] += a1.av * wv.x; acc[1][1] += a1.av * wv.y; \
            acc[1][2] += a1.av * wv.z; acc[1][3] += a1.av * wv.w; \
            acc[2][0] += a2.av * wv.x; acc[2][1] += a2.av * wv.y; \
            acc[2][2] += a2.av * wv.z; acc[2][3] += a2.av * wv.w; \
            acc[3][0] += a3.av * wv.x; acc[3][1] += a3.av * wv.y; \
            acc[3][2] += a3.av * wv.z; acc[3][3] += a3.av * wv.w;
        STEP(x, w0)
        STEP(y, w1)
        STEP(z, w2)
        STEP(w, w3)
        #undef STEP
    }

    float4 bv = make_float4(0.f, 0.f, 0.f, 0.f);
    if (bias) bv = *(const float4*)&bias[col0 + c0];

    #pragma unroll
    for (int i = 0; i < 4; i++) {
        int gr = row0 + r0 + i;
        if (gr < nrows) {
            float4 v;
            v.x = acc[i][0] + bv.x;
            v.y = acc[i][1] + bv.y;
            v.z = acc[i][2] + bv.z;
            v.w = acc[i][3] + bv.w;
            if (relu) {
                v.x = fmaxf(v.x, 0.f); v.y = fmaxf(v.y, 0.f);
                v.z = fmaxf(v.z, 0.f); v.w = fmaxf(v.w, 0.f);
            }
            if (rowscale) {
                float rs = rowscale[gr];
                v.x *= rs; v.y *= rs; v.z *= rs; v.w *= rs;
            }
            *(float4*)&out[(size_t)gr * outw + col0 + c0] = v;
        }
    }
}

extern "C" void kernel_launch(void* const* d_in, const int* in_sizes, int n_in,
                              void* d_out, int out_size, void* d_ws, size_t ws_size,
                              hipStream_t stream)
{
    const float* feat = (const float*)d_in[0];
    const int* src    = (const int*)d_in[1];
    const int* dst    = (const int*)d_in[2];
    const float* W0   = (const float*)d_in[3];
    const float* b0   = (const float*)d_in[4];
    const float* W1   = (const float*)d_in[5];
    const float* b1   = (const float*)d_in[6];
    const float* W2   = (const float*)d_in[7];
    const float* b2   = (const float*)d_in[8];
    float* out = (float*)d_out;

    const int N = N_NODES;
    const int E = N_EDGES;

    // ---- workspace layout (4-byte units) ----
    char* ws = (char*)d_ws;
    float* norm_out = (float*)ws;                    // N
    float* norm_in  = norm_out + N;                  // N
    int* cnt_out    = (int*)(norm_in + N);           // N
    int* cnt_in     = cnt_out + N;                   // N   (contiguous w/ cnt_out)
    int* row_start  = cnt_in + N;                    // SCAN_PAD + 4
    int* cursor     = row_start + (SCAN_PAD + 4);    // SCAN_PAD
    int* blockSums  = cursor + SCAN_PAD;             // 256
    int* csr        = blockSums + 268;               // E (268 keeps 16B alignment)
    float* bufA     = (float*)(csr + E);             // N*128
    float* bufB     = bufA + (size_t)N * 128;        // N*128

    // ---- CSR build ----
    hipMemsetAsync(cnt_out, 0, 2 * (size_t)N * sizeof(int), stream);
    hist_kernel<<<(E + 255) / 256, 256, 0, stream>>>(src, dst, cnt_out, cnt_in, E);
    norm_kernel<<<(2 * N + 255) / 256, 256, 0, stream>>>(cnt_out, norm_out, 2 * N);
    scan1_kernel<<<NB_SCAN, 256, 0, stream>>>(cnt_in, row_start, blockSums, N);
    scan2_kernel<<<1, 256, 0, stream>>>(blockSums, NB_SCAN);
    scan3_kernel<<<NB_SCAN, 256, 0, stream>>>(row_start, cursor, blockSums);
    scatter_kernel<<<(E + 255) / 256, 256, 0, stream>>>(src, dst, cursor, csr, E);

    const int gatherBlocks = (N * 16 + 255) / 256;   // 16 lanes/row
    const int rowBlocks = (N + 63) / 64;

    // ---- Layer 1: pull-agg(feat*norm_out)*norm_in -> bufA; relu(bufA@W0+b0)*norm_out -> bufB
    gather_kernel<128, true, false><<<gatherBlocks, 256, 0, stream>>>(
        feat, csr, row_start, norm_out, norm_in, nullptr, bufA);
    matmul_kernel<<<dim3(rowBlocks, 2), 256, 0, stream>>>(bufA, W0, b0, norm_out, bufB, N, 128, 1);

    // ---- Layer 2: pull-agg(bufB)*norm_in -> bufA; relu(bufA@W1+b1)*norm_out -> bufB
    gather_kernel<128, false, false><<<gatherBlocks, 256, 0, stream>>>(
        bufB, csr, row_start, nullptr, norm_in, nullptr, bufA);
    matmul_kernel<<<dim3(rowBlocks, 2), 256, 0, stream>>>(bufA, W1, b1, norm_out, bufB, N, 128, 1);

    // ---- Layer 3 (commuted): t = bufB@W2 -> bufA (N x 64); out = pull-agg(t)*norm_in + b2
    matmul_kernel<<<dim3(rowBlocks, 1), 256, 0, stream>>>(bufB, W2, nullptr, nullptr, bufA, N, 64, 0);
    gather_kernel<64, false, true><<<gatherBlocks, 256, 0, stream>>>(
        bufA, csr, row_start, nullptr, norm_in, b2, out);
}

// Round 5
// 781.314 us; speedup vs baseline: 7.4113x; 1.0805x over previous
//
#include <hip/hip_runtime.h>
#include <hip/hip_bf16.h>

#define N_NODES 170000
#define N_EDGES 1200000
#define SCAN_PAD 171008          // 167 blocks * 1024
#define NB_SCAN 167

// ---------------- histogram: in/out degree counts (int atomics) ----------------
__global__ __launch_bounds__(256) void hist_kernel(
    const int* __restrict__ src, const int* __restrict__ dst,
    int* __restrict__ cnt_out, int* __restrict__ cnt_in, int nedges)
{
    int i = blockIdx.x * 256 + threadIdx.x;
    if (i < nedges) {
        atomicAdd(&cnt_out[src[i]], 1);
        atomicAdd(&cnt_in[dst[i]], 1);
    }
}

// ---------------- norm = 1/sqrt(max(cnt,1)) ----------------
__global__ __launch_bounds__(256) void norm_kernel(
    const int* __restrict__ cnt, float* __restrict__ norm, int n)
{
    int i = blockIdx.x * 256 + threadIdx.x;
    if (i < n) norm[i] = rsqrtf(fmaxf((float)cnt[i], 1.0f));
}

// ---------------- fp32 -> bf16 row cast (feat) ----------------
__global__ __launch_bounds__(256) void f2bf_kernel(
    const float* __restrict__ in, __hip_bfloat16* __restrict__ outp, int n8)
{
    int i = blockIdx.x * 256 + threadIdx.x;
    if (i >= n8) return;
    float4 a = *(const float4*)&in[(size_t)i * 8];
    float4 b = *(const float4*)&in[(size_t)i * 8 + 4];
    float4 packed;
    __hip_bfloat162* p = (__hip_bfloat162*)&packed;
    p[0].x = __float2bfloat16(a.x); p[0].y = __float2bfloat16(a.y);
    p[1].x = __float2bfloat16(a.z); p[1].y = __float2bfloat16(a.w);
    p[2].x = __float2bfloat16(b.x); p[2].y = __float2bfloat16(b.y);
    p[3].x = __float2bfloat16(b.z); p[3].y = __float2bfloat16(b.w);
    *(float4*)&outp[(size_t)i * 8] = packed;
}

// ---------------- 3-phase exclusive scan of cnt_in -> row_start ----------------
__global__ __launch_bounds__(256) void scan1_kernel(
    const int* __restrict__ in, int* __restrict__ partial,
    int* __restrict__ blockSums, int n)
{
    __shared__ int sdata[256];
    int t = threadIdx.x;
    int base = blockIdx.x * 1024 + t * 4;
    int4 v = make_int4(0, 0, 0, 0);
    if (base + 3 < n) v = *(const int4*)&in[base];
    else {
        if (base + 0 < n) v.x = in[base + 0];
        if (base + 1 < n) v.y = in[base + 1];
        if (base + 2 < n) v.z = in[base + 2];
        if (base + 3 < n) v.w = in[base + 3];
    }
    int tsum = v.x + v.y + v.z + v.w;
    sdata[t] = tsum;
    __syncthreads();
    for (int off = 1; off < 256; off <<= 1) {
        int add = 0;
        if (t >= off) add = sdata[t - off];
        __syncthreads();
        if (t >= off) sdata[t] += add;
        __syncthreads();
    }
    int excl = sdata[t] - tsum;
    int4 o;
    o.x = excl;
    o.y = o.x + v.x;
    o.z = o.y + v.y;
    o.w = o.z + v.z;
    *(int4*)&partial[base] = o;   // partial buffer padded to SCAN_PAD+4
    if (t == 255) blockSums[blockIdx.x] = sdata[255];
}

__global__ __launch_bounds__(256) void scan2_kernel(int* __restrict__ blockSums, int nb)
{
    __shared__ int sdata[256];
    int t = threadIdx.x;
    int val = (t < nb) ? blockSums[t] : 0;
    sdata[t] = val;
    __syncthreads();
    for (int off = 1; off < 256; off <<= 1) {
        int add = 0;
        if (t >= off) add = sdata[t - off];
        __syncthreads();
        if (t >= off) sdata[t] += add;
        __syncthreads();
    }
    if (t < nb) blockSums[t] = sdata[t] - val;   // exclusive
}

__global__ __launch_bounds__(256) void scan3_kernel(
    int* __restrict__ row_start, int* __restrict__ cursor,
    const int* __restrict__ blockSums)
{
    int off = blockSums[blockIdx.x];
    int base = blockIdx.x * 1024 + threadIdx.x * 4;
    int4 v = *(const int4*)&row_start[base];
    v.x += off; v.y += off; v.z += off; v.w += off;
    *(int4*)&row_start[base] = v;
    *(int4*)&cursor[base] = v;
}

// ---------------- scatter src ids into dst-sorted CSR ----------------
__global__ __launch_bounds__(256) void scatter_kernel(
    const int* __restrict__ src, const int* __restrict__ dst,
    int* __restrict__ cursor, int* __restrict__ csr, int nedges)
{
    int i = blockIdx.x * 256 + threadIdx.x;
    if (i < nedges) {
        int p = atomicAdd(&cursor[dst[i]], 1);
        csr[p] = src[i];
    }
}

// ---------------- pull aggregation: 16-lane group per dst row, bf16 features ----
// R4 post-mortem: gather was traffic-bound (~4.6 TB/s fabric). bf16 features
// halve per-edge bytes (256 B for W=128). Accumulation stays fp32.
// out[d] = norm_in[d] * sum_{s in in(d)} h[s] * (SCALE_SRC ? norm_out[s] : 1)  (+ bias)
template<int W, bool SCALE_SRC, bool BIAS>
__global__ __launch_bounds__(256) void gather_kernel(
    const __hip_bfloat16* __restrict__ h, const int* __restrict__ csr,
    const int* __restrict__ row_start, const float* __restrict__ norm_out,
    const float* __restrict__ norm_in, const float* __restrict__ bias,
    float* __restrict__ out)
{
    int tid = blockIdx.x * 256 + threadIdx.x;
    int row = tid >> 4;                 // 16 lanes per row
    int l = threadIdx.x & 15;           // lane within group
    int gbase = threadIdx.x & 48;       // group's base lane within the wave
    if (row >= N_NODES) return;
    int beg = row_start[row];
    int end = row_start[row + 1];
    float acc[8] = {};
    for (int j = beg; j < end; j += 16) {
        int cnt = min(16, end - j);
        int sv = 0;
        float nv = 0.f;
        if (j + l < end) {
            sv = csr[j + l];                       // coalesced edge-id load
            if (SCALE_SRC) nv = norm_out[sv];
        }
        for (int i = 0; i < cnt; i++) {
            int s = __shfl(sv, gbase + i);
            if (W == 128) {
                // 8 bf16 per lane: one 16 B load covers the 128-wide row
                float4 raw = *(const float4*)(h + (size_t)s * 128 + l * 8);
                const __hip_bfloat162* pp = (const __hip_bfloat162*)&raw;
                float2 f0 = __bfloat1622float2(pp[0]);
                float2 f1 = __bfloat1622float2(pp[1]);
                float2 f2 = __bfloat1622float2(pp[2]);
                float2 f3 = __bfloat1622float2(pp[3]);
                if (SCALE_SRC) {
                    float sc = __shfl(nv, gbase + i);
                    acc[0] += f0.x * sc; acc[1] += f0.y * sc;
                    acc[2] += f1.x * sc; acc[3] += f1.y * sc;
                    acc[4] += f2.x * sc; acc[5] += f2.y * sc;
                    acc[6] += f3.x * sc; acc[7] += f3.y * sc;
                } else {
                    acc[0] += f0.x; acc[1] += f0.y;
                    acc[2] += f1.x; acc[3] += f1.y;
                    acc[4] += f2.x; acc[5] += f2.y;
                    acc[6] += f3.x; acc[7] += f3.y;
                }
            } else {
                // W==64: 4 bf16 per lane (8 B load)
                float2 raw = *(const float2*)(h + (size_t)s * 64 + l * 4);
                const __hip_bfloat162* pp = (const __hip_bfloat162*)&raw;
                float2 f0 = __bfloat1622float2(pp[0]);
                float2 f1 = __bfloat1622float2(pp[1]);
                acc[0] += f0.x; acc[1] += f0.y;
                acc[2] += f1.x; acc[3] += f1.y;
            }
        }
    }
    float ni = norm_in[row];
    if (W == 128) {
        float4 o0 = make_float4(acc[0] * ni, acc[1] * ni, acc[2] * ni, acc[3] * ni);
        float4 o1 = make_float4(acc[4] * ni, acc[5] * ni, acc[6] * ni, acc[7] * ni);
        float* op = &out[(size_t)row * 128 + l * 8];
        *(float4*)op = o0;
        *(float4*)(op + 4) = o1;
    } else {
        float4 o0 = make_float4(acc[0] * ni, acc[1] * ni, acc[2] * ni, acc[3] * ni);
        if (BIAS) {
            float4 b = *(const float4*)&bias[l * 4];
            o0.x += b.x; o0.y += b.y; o0.z += b.z; o0.w += b.w;
        }
        *(float4*)&out[(size_t)row * 64 + l * 4] = o0;
    }
}

// ---------------- fused dense: act(A @ W + b) * rowscale -> fp32 or bf16 ----------------
// K fixed = 128. Tile: 64 rows x 64 cols per block, 256 threads, 4x4 per thread.
// #pragma unroll 2: bounded so the compiler can't hoist all 32 bodies (R1 full
// unroll spilled: VGPR=256, 2.9 GB scratch writes).
template<bool OUT_BF>
__global__ __launch_bounds__(256) void matmul_kernel(
    const float* __restrict__ A, const float* __restrict__ W,
    const float* __restrict__ bias, const float* __restrict__ rowscale,
    float* __restrict__ outf, __hip_bfloat16* __restrict__ outbf,
    int nrows, int outw, int relu)
{
    __shared__ float As[64][132];
    __shared__ float Ws[128][64];

    const int t = threadIdx.x;
    const int row0 = blockIdx.x * 64;
    const int col0 = blockIdx.y * 64;

    #pragma unroll
    for (int i = 0; i < 8; i++) {
        int idx = t + i * 256;
        int k = idx >> 4;
        int c4 = idx & 15;
        float4 v = *(const float4*)&W[(size_t)k * outw + col0 + c4 * 4];
        *(float4*)&Ws[k][c4 * 4] = v;
    }

    #pragma unroll
    for (int i = 0; i < 8; i++) {
        int idx = t + i * 256;
        int r = idx >> 5;
        int k4 = idx & 31;
        int gr = row0 + r;
        float4 v = make_float4(0.f, 0.f, 0.f, 0.f);
        if (gr < nrows) v = *(const float4*)&A[(size_t)gr * 128 + k4 * 4];
        *(float4*)&As[r][k4 * 4] = v;
    }
    __syncthreads();

    const int tx = t & 15;
    const int ty = t >> 4;
    const int r0 = ty * 4;
    const int c0 = tx * 4;

    float acc[4][4] = {};
    #pragma unroll 2
    for (int kk = 0; kk < 128; kk += 4) {
        float4 a0 = *(const float4*)&As[r0 + 0][kk];
        float4 a1 = *(const float4*)&As[r0 + 1][kk];
        float4 a2 = *(const float4*)&As[r0 + 2][kk];
        float4 a3 = *(const float4*)&As[r0 + 3][kk];
        float4 w0 = *(const float4*)&Ws[kk + 0][c0];
        float4 w1 = *(const float4*)&Ws[kk + 1][c0];
        float4 w2 = *(const float4*)&Ws[kk + 2][c0];
        float4 w3 = *(const float4*)&Ws[kk + 3][c0];

        #define STEP(av, wv) \
            acc[0][0] += a0.av * wv.x; acc[0][1] += a0.av * wv.y; \
            acc[0][2] += a0.av * wv.z; acc[0][3] += a0.av * wv.w; \
            acc[1][0] += a1.av * wv.x; acc[1][1] += a1.av * wv.y; \
            acc[1][2] += a1.av * wv.z; acc[1][3] += a1.av * wv.w; \
            acc[2][0] += a2.av * wv.x; acc[2][1] += a2.av * wv.y; \
            acc[2][2] += a2.av * wv.z; acc[2][3] += a2.av * wv.w; \
            acc[3][0] += a3.av * wv.x; acc[3][1] += a3.av * wv.y; \
            acc[3][2] += a3.av * wv.z; acc[3][3] += a3.av * wv.w;
        STEP(x, w0)
        STEP(y, w1)
        STEP(z, w2)
        STEP(w, w3)
        #undef STEP
    }

    float4 bv = make_float4(0.f, 0.f, 0.f, 0.f);
    if (bias) bv = *(const float4*)&bias[col0 + c0];

    #pragma unroll
    for (int i = 0; i < 4; i++) {
        int gr = row0 + r0 + i;
        if (gr < nrows) {
            float4 v;
            v.x = acc[i][0] + bv.x;
            v.y = acc[i][1] + bv.y;
            v.z = acc[i][2] + bv.z;
            v.w = acc[i][3] + bv.w;
            if (relu) {
                v.x = fmaxf(v.x, 0.f); v.y = fmaxf(v.y, 0.f);
                v.z = fmaxf(v.z, 0.f); v.w = fmaxf(v.w, 0.f);
            }
            if (rowscale) {
                float rs = rowscale[gr];
                v.x *= rs; v.y *= rs; v.z *= rs; v.w *= rs;
            }
            if (OUT_BF) {
                float2 packed;
                __hip_bfloat162* p = (__hip_bfloat162*)&packed;
                p[0].x = __float2bfloat16(v.x); p[0].y = __float2bfloat16(v.y);
                p[1].x = __float2bfloat16(v.z); p[1].y = __float2bfloat16(v.w);
                *(float2*)&outbf[(size_t)gr * outw + col0 + c0] = packed;
            } else {
                *(float4*)&outf[(size_t)gr * outw + col0 + c0] = v;
            }
        }
    }
}

extern "C" void kernel_launch(void* const* d_in, const int* in_sizes, int n_in,
                              void* d_out, int out_size, void* d_ws, size_t ws_size,
                              hipStream_t stream)
{
    const float* feat = (const float*)d_in[0];
    const int* src    = (const int*)d_in[1];
    const int* dst    = (const int*)d_in[2];
    const float* W0   = (const float*)d_in[3];
    const float* b0   = (const float*)d_in[4];
    const float* W1   = (const float*)d_in[5];
    const float* b1   = (const float*)d_in[6];
    const float* W2   = (const float*)d_in[7];
    const float* b2   = (const float*)d_in[8];
    float* out = (float*)d_out;

    const int N = N_NODES;
    const int E = N_EDGES;

    // ---- workspace layout (4-byte units) ----
    char* ws = (char*)d_ws;
    float* norm_out = (float*)ws;                    // N
    float* norm_in  = norm_out + N;                  // N
    int* cnt_out    = (int*)(norm_in + N);           // N
    int* cnt_in     = cnt_out + N;                   // N   (contiguous w/ cnt_out)
    int* row_start  = cnt_in + N;                    // SCAN_PAD + 4
    int* cursor     = row_start + (SCAN_PAD + 4);    // SCAN_PAD
    int* blockSums  = cursor + SCAN_PAD;             // 256
    int* csr        = blockSums + 268;               // E (268 keeps 16B alignment)
    float* bufA     = (float*)(csr + E);             // N*128 fp32 (agg output)
    float* bufB     = bufA + (size_t)N * 128;        // N*128 fp32 (h2)
    // one reusable bf16 N*128 buffer: featbf -> h1bf -> tbf (sequential lifetimes)
    __hip_bfloat16* bfbuf = (__hip_bfloat16*)(bufB + (size_t)N * 128);

    // ---- CSR build + feat cast ----
    hipMemsetAsync(cnt_out, 0, 2 * (size_t)N * sizeof(int), stream);
    hist_kernel<<<(E + 255) / 256, 256, 0, stream>>>(src, dst, cnt_out, cnt_in, E);
    norm_kernel<<<(2 * N + 255) / 256, 256, 0, stream>>>(cnt_out, norm_out, 2 * N);
    scan1_kernel<<<NB_SCAN, 256, 0, stream>>>(cnt_in, row_start, blockSums, N);
    scan2_kernel<<<1, 256, 0, stream>>>(blockSums, NB_SCAN);
    scan3_kernel<<<NB_SCAN, 256, 0, stream>>>(row_start, cursor, blockSums);
    scatter_kernel<<<(E + 255) / 256, 256, 0, stream>>>(src, dst, cursor, csr, E);
    f2bf_kernel<<<(N * 16 + 255) / 256, 256, 0, stream>>>(feat, bfbuf, N * 16);

    const int gatherBlocks = (N * 16 + 255) / 256;   // 16 lanes/row
    const int rowBlocks = (N + 63) / 64;

    // ---- Layer 1: agg(featbf*norm_out)*norm_in -> bufA; relu(bufA@W0+b0)*norm_out -> h1bf
    gather_kernel<128, true, false><<<gatherBlocks, 256, 0, stream>>>(
        bfbuf, csr, row_start, norm_out, norm_in, nullptr, bufA);
    matmul_kernel<true><<<dim3(rowBlocks, 2), 256, 0, stream>>>(
        bufA, W0, b0, norm_out, nullptr, bfbuf, N, 128, 1);

    // ---- Layer 2: agg(h1bf)*norm_in -> bufA; relu(bufA@W1+b1)*norm_out -> bufB (fp32 h2)
    gather_kernel<128, false, false><<<gatherBlocks, 256, 0, stream>>>(
        bfbuf, csr, row_start, nullptr, norm_in, nullptr, bufA);
    matmul_kernel<false><<<dim3(rowBlocks, 2), 256, 0, stream>>>(
        bufA, W1, b1, norm_out, bufB, nullptr, N, 128, 1);

    // ---- Layer 3 (commuted): tbf = bf16(bufB@W2); out = agg(tbf)*norm_in + b2
    matmul_kernel<true><<<dim3(rowBlocks, 1), 256, 0, stream>>>(
        bufB, W2, nullptr, nullptr, nullptr, bfbuf, N, 64, 0);
    gather_kernel<64, false, true><<<gatherBlocks, 256, 0, stream>>>(
        bfbuf, csr, row_start, nullptr, norm_in, b2, out);
}

// Round 6
// 721.016 us; speedup vs baseline: 8.0311x; 1.0836x over previous
//
#include <hip/hip_runtime.h>
#include <hip/hip_bf16.h>

#define N_NODES 170000
#define N_EDGES 1200000
#define SCAN_PAD 171008          // 167 blocks * 1024
#define NB_SCAN 167

typedef short bf16x8 __attribute__((ext_vector_type(8)));
typedef float f32x4 __attribute__((ext_vector_type(4)));

__device__ __forceinline__ void bf_split(float v, __hip_bfloat16& h, __hip_bfloat16& l)
{
    h = __float2bfloat16(v);
    l = __float2bfloat16(v - __bfloat162float(h));
}

// ---------------- histogram: in/out degree counts (int atomics) ----------------
__global__ __launch_bounds__(256) void hist_kernel(
    const int* __restrict__ src, const int* __restrict__ dst,
    int* __restrict__ cnt_out, int* __restrict__ cnt_in, int nedges)
{
    int i = blockIdx.x * 256 + threadIdx.x;
    if (i < nedges) {
        atomicAdd(&cnt_out[src[i]], 1);
        atomicAdd(&cnt_in[dst[i]], 1);
    }
}

// ---------------- norm = 1/sqrt(max(cnt,1)) ----------------
__global__ __launch_bounds__(256) void norm_kernel(
    const int* __restrict__ cnt, float* __restrict__ norm, int n)
{
    int i = blockIdx.x * 256 + threadIdx.x;
    if (i < n) norm[i] = rsqrtf(fmaxf((float)cnt[i], 1.0f));
}

// ---------------- fp32 -> bf16 row cast (feat) ----------------
__global__ __launch_bounds__(256) void f2bf_kernel(
    const float* __restrict__ in, __hip_bfloat16* __restrict__ outp, int n8)
{
    int i = blockIdx.x * 256 + threadIdx.x;
    if (i >= n8) return;
    float4 a = *(const float4*)&in[(size_t)i * 8];
    float4 b = *(const float4*)&in[(size_t)i * 8 + 4];
    float4 packed;
    __hip_bfloat162* p = (__hip_bfloat162*)&packed;
    p[0].x = __float2bfloat16(a.x); p[0].y = __float2bfloat16(a.y);
    p[1].x = __float2bfloat16(a.z); p[1].y = __float2bfloat16(a.w);
    p[2].x = __float2bfloat16(b.x); p[2].y = __float2bfloat16(b.y);
    p[3].x = __float2bfloat16(b.z); p[3].y = __float2bfloat16(b.w);
    *(float4*)&outp[(size_t)i * 8] = packed;
}

// ---------------- W (K x Nout fp32) -> transposed split planes Wt[n][k] bf16 ----------------
__global__ __launch_bounds__(256) void wsplit_kernel(
    const float* __restrict__ W, int nout,
    __hip_bfloat16* __restrict__ Whi, __hip_bfloat16* __restrict__ Wlo)
{
    int i = blockIdx.x * 256 + threadIdx.x;   // over 128*nout
    if (i >= 128 * nout) return;
    int k = i / nout, n = i - k * nout;
    float v = W[i];
    __hip_bfloat16 h, l;
    bf_split(v, h, l);
    Whi[n * 128 + k] = h;
    Wlo[n * 128 + k] = l;
}

// ---------------- 3-phase exclusive scan of cnt_in -> row_start ----------------
__global__ __launch_bounds__(256) void scan1_kernel(
    const int* __restrict__ in, int* __restrict__ partial,
    int* __restrict__ blockSums, int n)
{
    __shared__ int sdata[256];
    int t = threadIdx.x;
    int base = blockIdx.x * 1024 + t * 4;
    int4 v = make_int4(0, 0, 0, 0);
    if (base + 3 < n) v = *(const int4*)&in[base];
    else {
        if (base + 0 < n) v.x = in[base + 0];
        if (base + 1 < n) v.y = in[base + 1];
        if (base + 2 < n) v.z = in[base + 2];
        if (base + 3 < n) v.w = in[base + 3];
    }
    int tsum = v.x + v.y + v.z + v.w;
    sdata[t] = tsum;
    __syncthreads();
    for (int off = 1; off < 256; off <<= 1) {
        int add = 0;
        if (t >= off) add = sdata[t - off];
        __syncthreads();
        if (t >= off) sdata[t] += add;
        __syncthreads();
    }
    int excl = sdata[t] - tsum;
    int4 o;
    o.x = excl;
    o.y = o.x + v.x;
    o.z = o.y + v.y;
    o.w = o.z + v.z;
    *(int4*)&partial[base] = o;   // partial buffer padded to SCAN_PAD+4
    if (t == 255) blockSums[blockIdx.x] = sdata[255];
}

__global__ __launch_bounds__(256) void scan2_kernel(int* __restrict__ blockSums, int nb)
{
    __shared__ int sdata[256];
    int t = threadIdx.x;
    int val = (t < nb) ? blockSums[t] : 0;
    sdata[t] = val;
    __syncthreads();
    for (int off = 1; off < 256; off <<= 1) {
        int add = 0;
        if (t >= off) add = sdata[t - off];
        __syncthreads();
        if (t >= off) sdata[t] += add;
        __syncthreads();
    }
    if (t < nb) blockSums[t] = sdata[t] - val;   // exclusive
}

__global__ __launch_bounds__(256) void scan3_kernel(
    int* __restrict__ row_start, int* __restrict__ cursor,
    const int* __restrict__ blockSums)
{
    int off = blockSums[blockIdx.x];
    int base = blockIdx.x * 1024 + threadIdx.x * 4;
    int4 v = *(const int4*)&row_start[base];
    v.x += off; v.y += off; v.z += off; v.w += off;
    *(int4*)&row_start[base] = v;
    *(int4*)&cursor[base] = v;
}

// ---------------- scatter src ids into dst-sorted CSR ----------------
__global__ __launch_bounds__(256) void scatter_kernel(
    const int* __restrict__ src, const int* __restrict__ dst,
    int* __restrict__ cursor, int* __restrict__ csr, int nedges)
{
    int i = blockIdx.x * 256 + threadIdx.x;
    if (i < nedges) {
        int p = atomicAdd(&cursor[dst[i]], 1);
        csr[p] = src[i];
    }
}

// ---------------- pull aggregation: 16-lane group per dst row, bf16 features ----
// Accumulates fp32. For W=128 emits SPLIT bf16 planes (hi+lo ~ fp32 precision,
// feeds the MFMA GEMM); for W=64 (final layer) emits fp32 + bias.
template<int W, bool SCALE_SRC, bool SPLIT_OUT, bool BIAS>
__global__ __launch_bounds__(256) void gather_kernel(
    const __hip_bfloat16* __restrict__ h, const int* __restrict__ csr,
    const int* __restrict__ row_start, const float* __restrict__ norm_out,
    const float* __restrict__ norm_in, const float* __restrict__ bias,
    float* __restrict__ outf, __hip_bfloat16* __restrict__ ohi,
    __hip_bfloat16* __restrict__ olo)
{
    int tid = blockIdx.x * 256 + threadIdx.x;
    int row = tid >> 4;                 // 16 lanes per row
    int l = threadIdx.x & 15;           // lane within group
    int gbase = threadIdx.x & 48;       // group's base lane within the wave
    if (row >= N_NODES) return;
    int beg = row_start[row];
    int end = row_start[row + 1];
    float acc[8] = {};
    for (int j = beg; j < end; j += 16) {
        int cnt = min(16, end - j);
        int sv = 0;
        float nv = 0.f;
        if (j + l < end) {
            sv = csr[j + l];                       // coalesced edge-id load
            if (SCALE_SRC) nv = norm_out[sv];
        }
        for (int i = 0; i < cnt; i++) {
            int s = __shfl(sv, gbase + i);
            if (W == 128) {
                float4 raw = *(const float4*)(h + (size_t)s * 128 + l * 8);
                const __hip_bfloat162* pp = (const __hip_bfloat162*)&raw;
                float2 f0 = __bfloat1622float2(pp[0]);
                float2 f1 = __bfloat1622float2(pp[1]);
                float2 f2 = __bfloat1622float2(pp[2]);
                float2 f3 = __bfloat1622float2(pp[3]);
                if (SCALE_SRC) {
                    float sc = __shfl(nv, gbase + i);
                    acc[0] += f0.x * sc; acc[1] += f0.y * sc;
                    acc[2] += f1.x * sc; acc[3] += f1.y * sc;
                    acc[4] += f2.x * sc; acc[5] += f2.y * sc;
                    acc[6] += f3.x * sc; acc[7] += f3.y * sc;
                } else {
                    acc[0] += f0.x; acc[1] += f0.y;
                    acc[2] += f1.x; acc[3] += f1.y;
                    acc[4] += f2.x; acc[5] += f2.y;
                    acc[6] += f3.x; acc[7] += f3.y;
                }
            } else {
                float2 raw = *(const float2*)(h + (size_t)s * 64 + l * 4);
                const __hip_bfloat162* pp = (const __hip_bfloat162*)&raw;
                float2 f0 = __bfloat1622float2(pp[0]);
                float2 f1 = __bfloat1622float2(pp[1]);
                acc[0] += f0.x; acc[1] += f0.y;
                acc[2] += f1.x; acc[3] += f1.y;
            }
        }
    }
    float ni = norm_in[row];
    if (W == 128 && SPLIT_OUT) {
        float4 ph, pl;
        __hip_bfloat16* hp = (__hip_bfloat16*)&ph;
        __hip_bfloat16* lp = (__hip_bfloat16*)&pl;
        #pragma unroll
        for (int j = 0; j < 8; j++) bf_split(acc[j] * ni, hp[j], lp[j]);
        *(float4*)(ohi + (size_t)row * 128 + l * 8) = ph;
        *(float4*)(olo + (size_t)row * 128 + l * 8) = pl;
    } else if (W == 64) {
        float4 o0 = make_float4(acc[0] * ni, acc[1] * ni, acc[2] * ni, acc[3] * ni);
        if (BIAS) {
            float4 b = *(const float4*)&bias[l * 4];
            o0.x += b.x; o0.y += b.y; o0.z += b.z; o0.w += b.w;
        }
        *(float4*)&outf[(size_t)row * 64 + l * 4] = o0;
    }
}

// ---------------- MFMA GEMM: out = act(A @ W + b) * rowscale ----------------
// A in split bf16 planes (hi+lo ~ fp32), Wt in transposed split planes [n][k].
// 3-MFMA split product: hi*hi + lo*hi + hi*lo (lo*lo dropped, ~2^-16 rel).
// Per wave: two 16-row tiles x NT 16-col tiles, K=128 in 4 chunks of 32.
// No LDS, no barriers; W planes stay L1/L2-resident.
// #pragma unroll 1 on kc: prevents full-unroll load hoisting (R1 spill lesson).
template<int NT, bool RELU, bool BIAS, bool RS, bool SPLIT_OUT>
__global__ __launch_bounds__(256) void mfma_matmul_kernel(
    const __hip_bfloat16* __restrict__ Ahi, const __hip_bfloat16* __restrict__ Alo,
    const __hip_bfloat16* __restrict__ Wthi, const __hip_bfloat16* __restrict__ Wtlo,
    const float* __restrict__ bias, const float* __restrict__ rowscale,
    __hip_bfloat16* __restrict__ outhi, __hip_bfloat16* __restrict__ outlo,
    int nrows)
{
    const int OUTW = NT * 16;
    const int wave = threadIdx.x >> 6;
    const int lane = threadIdx.x & 63;
    const int n = lane & 15;       // col within tile (B/D); also row within tile for A
    const int q = lane >> 4;       // quad
    const int r0 = blockIdx.x * 128 + wave * 32;
    if (r0 >= nrows) return;
    const bool t1 = (r0 + 16) < nrows;          // nrows % 16 == 0 -> tiles are full
    const size_t a0off = (size_t)(r0 + n) * 128 + q * 8;
    const size_t a1off = (size_t)(t1 ? (r0 + 16 + n) : (r0 + n)) * 128 + q * 8;
    const size_t bbase = (size_t)n * 128 + q * 8;

    f32x4 acc0[NT], acc1[NT];
    const f32x4 zero = {0.f, 0.f, 0.f, 0.f};
    #pragma unroll
    for (int ct = 0; ct < NT; ct++) { acc0[ct] = zero; acc1[ct] = zero; }

    #pragma unroll 1
    for (int kc = 0; kc < 4; kc++) {
        bf16x8 ah0 = *(const bf16x8*)(Ahi + a0off + kc * 32);
        bf16x8 al0 = *(const bf16x8*)(Alo + a0off + kc * 32);
        bf16x8 ah1 = *(const bf16x8*)(Ahi + a1off + kc * 32);
        bf16x8 al1 = *(const bf16x8*)(Alo + a1off + kc * 32);
        #pragma unroll
        for (int ct = 0; ct < NT; ct++) {
            bf16x8 bh = *(const bf16x8*)(Wthi + (size_t)ct * 2048 + bbase + kc * 32);
            bf16x8 bl = *(const bf16x8*)(Wtlo + (size_t)ct * 2048 + bbase + kc * 32);
            acc0[ct] = __builtin_amdgcn_mfma_f32_16x16x32_bf16(ah0, bh, acc0[ct], 0, 0, 0);
            acc0[ct] = __builtin_amdgcn_mfma_f32_16x16x32_bf16(al0, bh, acc0[ct], 0, 0, 0);
            acc0[ct] = __builtin_amdgcn_mfma_f32_16x16x32_bf16(ah0, bl, acc0[ct], 0, 0, 0);
            acc1[ct] = __builtin_amdgcn_mfma_f32_16x16x32_bf16(ah1, bh, acc1[ct], 0, 0, 0);
            acc1[ct] = __builtin_amdgcn_mfma_f32_16x16x32_bf16(al1, bh, acc1[ct], 0, 0, 0);
            acc1[ct] = __builtin_amdgcn_mfma_f32_16x16x32_bf16(ah1, bl, acc1[ct], 0, 0, 0);
        }
    }

    float bcol[NT];
    #pragma unroll
    for (int ct = 0; ct < NT; ct++) bcol[ct] = BIAS ? bias[ct * 16 + n] : 0.f;

    // tile 0: rows r0 + q*4 + r
    #pragma unroll
    for (int r = 0; r < 4; r++) {
        int grow = r0 + q * 4 + r;
        float rs = RS ? rowscale[grow] : 1.f;
        #pragma unroll
        for (int ct = 0; ct < NT; ct++) {
            float v = acc0[ct][r] + bcol[ct];
            if (RELU) v = fmaxf(v, 0.f);
            v *= rs;
            size_t o = (size_t)grow * OUTW + ct * 16 + n;
            if (SPLIT_OUT) {
                __hip_bfloat16 h, l;
                bf_split(v, h, l);
                outhi[o] = h; outlo[o] = l;
            } else {
                outhi[o] = __float2bfloat16(v);
            }
        }
    }
    if (t1) {
        #pragma unroll
        for (int r = 0; r < 4; r++) {
            int grow = r0 + 16 + q * 4 + r;
            float rs = RS ? rowscale[grow] : 1.f;
            #pragma unroll
            for (int ct = 0; ct < NT; ct++) {
                float v = acc1[ct][r] + bcol[ct];
                if (RELU) v = fmaxf(v, 0.f);
                v *= rs;
                size_t o = (size_t)grow * OUTW + ct * 16 + n;
                if (SPLIT_OUT) {
                    __hip_bfloat16 h, l;
                    bf_split(v, h, l);
                    outhi[o] = h; outlo[o] = l;
                } else {
                    outhi[o] = __float2bfloat16(v);
                }
            }
        }
    }
}

extern "C" void kernel_launch(void* const* d_in, const int* in_sizes, int n_in,
                              void* d_out, int out_size, void* d_ws, size_t ws_size,
                              hipStream_t stream)
{
    const float* feat = (const float*)d_in[0];
    const int* src    = (const int*)d_in[1];
    const int* dst    = (const int*)d_in[2];
    const float* W0   = (const float*)d_in[3];
    const float* b0   = (const float*)d_in[4];
    const float* W1   = (const float*)d_in[5];
    const float* b1   = (const float*)d_in[6];
    const float* W2   = (const float*)d_in[7];
    const float* b2   = (const float*)d_in[8];
    float* out = (float*)d_out;

    const int N = N_NODES;
    const int E = N_EDGES;

    // ---- workspace layout ----
    char* ws = (char*)d_ws;
    float* norm_out = (float*)ws;                    // N
    float* norm_in  = norm_out + N;                  // N
    int* cnt_out    = (int*)(norm_in + N);           // N
    int* cnt_in     = cnt_out + N;                   // N
    int* row_start  = cnt_in + N;                    // SCAN_PAD + 4
    int* cursor     = row_start + (SCAN_PAD + 4);    // SCAN_PAD
    int* blockSums  = cursor + SCAN_PAD;             // 256
    int* csr        = blockSums + 268;               // E (268 keeps 16B alignment)
    __hip_bfloat16* Wt0hi = (__hip_bfloat16*)(csr + E);   // 16384 each
    __hip_bfloat16* Wt0lo = Wt0hi + 16384;
    __hip_bfloat16* Wt1hi = Wt0lo + 16384;
    __hip_bfloat16* Wt1lo = Wt1hi + 16384;
    __hip_bfloat16* Wt2hi = Wt1lo + 16384;           // 8192 each
    __hip_bfloat16* Wt2lo = Wt2hi + 8192;
    __hip_bfloat16* bfbuf = Wt2lo + 8192;            // N*128 (featbf -> h1bf -> tbf)
    __hip_bfloat16* Ahi   = bfbuf + (size_t)N * 128; // N*128
    __hip_bfloat16* Alo   = Ahi + (size_t)N * 128;   // N*128

    // ---- CSR build + casts/splits ----
    hipMemsetAsync(cnt_out, 0, 2 * (size_t)N * sizeof(int), stream);
    hist_kernel<<<(E + 255) / 256, 256, 0, stream>>>(src, dst, cnt_out, cnt_in, E);
    norm_kernel<<<(2 * N + 255) / 256, 256, 0, stream>>>(cnt_out, norm_out, 2 * N);
    scan1_kernel<<<NB_SCAN, 256, 0, stream>>>(cnt_in, row_start, blockSums, N);
    scan2_kernel<<<1, 256, 0, stream>>>(blockSums, NB_SCAN);
    scan3_kernel<<<NB_SCAN, 256, 0, stream>>>(row_start, cursor, blockSums);
    scatter_kernel<<<(E + 255) / 256, 256, 0, stream>>>(src, dst, cursor, csr, E);
    f2bf_kernel<<<(N * 16 + 255) / 256, 256, 0, stream>>>(feat, bfbuf, N * 16);
    wsplit_kernel<<<64, 256, 0, stream>>>(W0, 128, Wt0hi, Wt0lo);
    wsplit_kernel<<<64, 256, 0, stream>>>(W1, 128, Wt1hi, Wt1lo);
    wsplit_kernel<<<32, 256, 0, stream>>>(W2, 64, Wt2hi, Wt2lo);

    const int gatherBlocks = (N * 16 + 255) / 256;   // 16 lanes/row
    const int mmBlocks = (N + 127) / 128;            // 128 rows/block (2 tiles/wave)

    // ---- Layer 1: agg(featbf*no)*ni -> A split; relu(A@W0+b0)*no -> h1bf
    gather_kernel<128, true, true, false><<<gatherBlocks, 256, 0, stream>>>(
        bfbuf, csr, row_start, norm_out, norm_in, nullptr, nullptr, Ahi, Alo);
    mfma_matmul_kernel<8, true, true, true, false><<<mmBlocks, 256, 0, stream>>>(
        Ahi, Alo, Wt0hi, Wt0lo, b0, norm_out, bfbuf, nullptr, N);

    // ---- Layer 2: agg(h1bf)*ni -> A split; relu(A@W1+b1)*no -> A split (in-place)
    gather_kernel<128, false, true, false><<<gatherBlocks, 256, 0, stream>>>(
        bfbuf, csr, row_start, nullptr, norm_in, nullptr, nullptr, Ahi, Alo);
    mfma_matmul_kernel<8, true, true, true, true><<<mmBlocks, 256, 0, stream>>>(
        Ahi, Alo, Wt1hi, Wt1lo, b1, norm_out, Ahi, Alo, N);

    // ---- Layer 3 (commuted): tbf = bf16(h2@W2); out = agg(tbf)*ni + b2
    mfma_matmul_kernel<4, false, false, false, false><<<mmBlocks, 256, 0, stream>>>(
        Ahi, Alo, Wt2hi, Wt2lo, nullptr, nullptr, bfbuf, nullptr, N);
    gather_kernel<64, false, false, true><<<gatherBlocks, 256, 0, stream>>>(
        bfbuf, csr, row_start, nullptr, norm_in, b2, out, nullptr, nullptr);
}